// Round 4
// baseline (147.221 us; speedup 1.0000x reference)
//
#include <hip/hip_runtime.h>
#include <hip/hip_bf16.h>
#include <stdint.h>

typedef __bf16 bf16_t;
typedef float floatx4 __attribute__((ext_vector_type(4)));
typedef float floatx16 __attribute__((ext_vector_type(16)));
typedef __bf16 bf16x8 __attribute__((ext_vector_type(8)));
typedef __bf16 bf16x4 __attribute__((ext_vector_type(4)));
typedef unsigned int uintx4 __attribute__((ext_vector_type(4)));

// scale = DH^-0.5 * log2(e), folded into Q at GEMM epilogue so softmax uses raw exp2
#define QSCALE 0.1803368801111204f

// -------------------- async global->LDS (16B) --------------------
__device__ __forceinline__ void gl2lds16(const bf16_t* g, bf16_t* l) {
    __builtin_amdgcn_global_load_lds(
        (const __attribute__((address_space(1))) unsigned int*)g,
        (__attribute__((address_space(3))) unsigned int*)l,
        16, 0, 0);
}

// pack two f32 -> one dword of 2 bf16 (scalar casts; compiler fuses well, m240)
__device__ __forceinline__ unsigned pk2(float lo, float hi) {
    unsigned short a = __builtin_bit_cast(unsigned short, (bf16_t)lo);
    unsigned short b = __builtin_bit_cast(unsigned short, (bf16_t)hi);
    return (unsigned)a | ((unsigned)b << 16);
}

// -------------------- fp32 -> bf16 convert (x and W fused) --------------------
__global__ __launch_bounds__(256) void convert_kernel(const float* __restrict__ x,
                                                      bf16_t* __restrict__ xb,
                                                      const float* __restrict__ w,
                                                      bf16_t* __restrict__ wb,
                                                      int nx4) {   // x chunks; W chunks follow
    int i = blockIdx.x * 256 + threadIdx.x;
    const float* in; bf16_t* out; int j;
    if (i < nx4) { in = x; out = xb; j = i; }
    else         { in = w; out = wb; j = i - nx4; }
    float4 v = ((const float4*)in)[j];
    bf16x4 o;
    o.x = (bf16_t)v.x; o.y = (bf16_t)v.y; o.z = (bf16_t)v.z; o.w = (bf16_t)v.w;
    ((bf16x4*)out)[j] = o;
}

// -------------------- QKV projection GEMM (gemm_bt) --------------------
__global__ __launch_bounds__(256) void qkv_gemm(const bf16_t* __restrict__ X,   // [8192][512]
                                                const bf16_t* __restrict__ W,   // [1536][512]
                                                bf16_t* __restrict__ Q,         // [32][2048][64] (pre-scaled)
                                                bf16_t* __restrict__ K,         // [32][2048][64]
                                                bf16_t* __restrict__ Vt)        // [32][64][2048]
{
    __shared__ bf16_t As[128 * 64];
    __shared__ bf16_t Bs[128 * 64];

    const int tid  = threadIdx.x;
    const int wave = tid >> 6;
    const int lane = tid & 63;
    const int quad = lane >> 4;
    const int lrow = lane & 15;
    const int t7g  = lrow & 7;      // = row&7 of every fragment row this lane touches
    const int bm0 = blockIdx.x * 128;
    const int bn0 = blockIdx.y * 128;
    const int mw = (wave >> 1) * 64;
    const int nw = (wave & 1) * 64;
    const int wbase = tid & 192;   // wave*64, wave-uniform

    floatx4 acc[4][4];
#pragma unroll
    for (int i = 0; i < 4; i++)
#pragma unroll
        for (int j = 0; j < 4; j++) acc[i][j] = (floatx4)0.0f;

#pragma unroll 1
    for (int kb = 0; kb < 8; ++kb) {
        const int k0 = kb * 64;
        __syncthreads();
#pragma unroll
        for (int r = 0; r < 4; ++r) {
            int c = r * 256 + tid;
            int row = c >> 3, kc = c & 7;
            int skc = kc ^ (row & 7);   // swizzled source chunk
            gl2lds16(X + (size_t)(bm0 + row) * 512 + k0 + skc * 8,
                     As + (size_t)(r * 256 + wbase) * 8);
        }
#pragma unroll
        for (int r = 0; r < 4; ++r) {
            int c = r * 256 + tid;
            int row = c >> 3, kc = c & 7;
            int skc = kc ^ (row & 7);
            gl2lds16(W + (size_t)(bn0 + row) * 512 + k0 + skc * 8,
                     Bs + (size_t)(r * 256 + wbase) * 8);
        }
        __syncthreads();
#pragma unroll
        for (int ks = 0; ks < 2; ++ks) {
            bf16x8 af[4], bfr[4];
#pragma unroll
            for (int mi = 0; mi < 4; mi++)
                af[mi] = *(const bf16x8*)(As + (mw + mi * 16 + lrow) * 64 + (((ks * 4 + quad) ^ t7g) << 3));
#pragma unroll
            for (int ni = 0; ni < 4; ni++)
                bfr[ni] = *(const bf16x8*)(Bs + (nw + ni * 16 + lrow) * 64 + (((ks * 4 + quad) ^ t7g) << 3));
#pragma unroll
            for (int mi = 0; mi < 4; mi++)
#pragma unroll
                for (int ni = 0; ni < 4; ni++)
                    acc[mi][ni] = __builtin_amdgcn_mfma_f32_16x16x32_bf16(af[mi], bfr[ni], acc[mi][ni], 0, 0, 0);
        }
    }

    // epilogue: C/D layout col=lane&15, row=quad*4+reg  [verified m89]
#pragma unroll
    for (int mi = 0; mi < 4; mi++) {
        int mbase = bm0 + mw + mi * 16 + quad * 4;
        int b = mbase >> 11, n = mbase & 2047;   // r never crosses batch boundary (mbase%4==0)
#pragma unroll
        for (int ni = 0; ni < 4; ni++) {
            int o = bn0 + nw + ni * 16 + lrow;
            int s  = o >> 9;
            int h  = (o >> 6) & 7;
            int dh = o & 63;
            int bh = b * 8 + h;
            if (s == 2) {
                bf16x4 pv;
#pragma unroll
                for (int r = 0; r < 4; r++) pv[r] = (bf16_t)acc[mi][ni][r];
                *(bf16x4*)(Vt + ((size_t)bh * 64 + dh) * 2048 + n) = pv;   // 8B packed
            } else if (s == 0) {
#pragma unroll
                for (int r = 0; r < 4; r++)
                    Q[((size_t)bh * 2048 + n + r) * 64 + dh] = (bf16_t)(acc[mi][ni][r] * QSCALE);
            } else {
#pragma unroll
                for (int r = 0; r < 4; r++)
                    K[((size_t)bh * 2048 + n + r) * 64 + dh] = (bf16_t)acc[mi][ni][r];
            }
        }
    }
}

// -------------------- flash attention --------------------
// R9: (1) XCD swizzle: XCD x owns bh in [4x,4x+4) -> K/V staged from local L2
//     (FETCH 69.7MB was cross-XCD L3 re-fetch; working set 3MB < 4MB L2).
// (2) 32x32x16 MFMA: per-wave S-tile is exactly 32k x 32q -> QK^T 8->4 MFMAs,
//     PV 8->4 (two 32x32 d-tiles x two K=16 slices). D-layout col=lane&31,
//     row=(reg&3)+8*(reg>>2)+4*(lane>>5) [m74/m101]. permlane32_swap pairs
//     regs 0-7 (slice0) / 8-15 (slice1) across lane-halves, same trick as R8.
// (3) kt-unroll-2: explicit buf0/buf1 bodies -> all LDS addrs loop-invariant.
__global__ __launch_bounds__(256, 4) void flash_attn(const bf16_t* __restrict__ Q,   // [32][2048][64], pre-scaled
                                                     const bf16_t* __restrict__ K,   // [32][2048][64]
                                                     const bf16_t* __restrict__ Vt,  // [32][64][2048]
                                                     float* __restrict__ Out)        // [4][2048][512]
{
    __shared__ bf16_t Ks[2][64 * 64];   // 16 KB
    __shared__ bf16_t Vs[2][64 * 64];   // 16 KB  (Vs[d][key] layout)

    const int tid  = threadIdx.x;
    const int wave = tid >> 6;
    const int lane = tid & 63;
    const int l31  = lane & 31;
    const int h    = lane >> 5;      // lane half
    const int l7   = lane & 7;       // = row&7 for rows indexed by l31
    const int qhalf = wave >> 1;     // which 32 q-rows
    const int khalf = wave & 1;      // which 32 keys of each 64-key tile

    // XCD swizzle: bijective over 1024 blocks; XCD (raw%8) gets bh group of 4
    int raw = blockIdx.x + (blockIdx.y << 5);
    int swz = (raw & 7) * 128 + (raw >> 3);
    const int qt = swz & 31;
    const int bh = swz >> 5;
    const int b = bh >> 3, hd = bh & 7;

    // Q fragments (B-operand of 32x32x16: n=l31=q, k=h*8+j per 16-slice)
    int qg  = qt * 64 + qhalf * 32 + l31;
    int src = (qg == 0) ? 0 : qg - 1;
    const bf16_t* qbase = Q + ((size_t)bh * 2048 + src) * 64;
    bf16x8 qf0 = *(const bf16x8*)(qbase + 0 * 16 + h * 8);
    bf16x8 qf1 = *(const bf16x8*)(qbase + 1 * 16 + h * 8);
    bf16x8 qf2 = *(const bf16x8*)(qbase + 2 * 16 + h * 8);
    bf16x8 qf3 = *(const bf16x8*)(qbase + 3 * 16 + h * 8);

    floatx16 O0 = (floatx16)0.0f;   // d 0..31
    floatx16 O1 = (floatx16)0.0f;   // d 32..63
    float lacc = 0.0f;

    const bf16_t* kb = K + ((size_t)bh * 2048) * 64;
    const bf16_t* vb = Vt + ((size_t)bh * 64) * 2048;

    // ---- hoisted staging geometry (per lane) ----
    const int ch0 = wave * 64 + lane;          // chunk ids 0..255 / 256..511
    const int r0s = ch0 >> 3, c0s = (ch0 & 7) ^ (r0s & 7);
    const int ch1 = 256 + ch0;
    const int r1s = ch1 >> 3, c1s = (ch1 & 7) ^ (r1s & 7);
    const bf16_t* gk0 = kb + r0s * 64 + c0s * 8;      // + kt*4096
    const bf16_t* gk1 = kb + r1s * 64 + c1s * 8;
    const bf16_t* gv0 = vb + (size_t)r0s * 2048 + c0s * 8;   // + kt*64
    const bf16_t* gv1 = vb + (size_t)r1s * 2048 + c1s * 8;
    const int woff = wave * 512;   // wave-uniform LDS dst

    auto STAGE = [&](int bufI, int kt) {
        gl2lds16(gk0 + (size_t)kt * 4096, Ks[bufI] + woff);
        gl2lds16(gk1 + (size_t)kt * 4096, Ks[bufI] + 2048 + woff);
        gl2lds16(gv0 + kt * 64, Vs[bufI] + woff);
        gl2lds16(gv1 + kt * 64, Vs[bufI] + 2048 + woff);
    };

    // ---- hoisted fragment read offsets (elements) ----
    const int krow = (khalf * 32 + l31) * 64;          // K row (row&7 == l7)
    const int koff0 = krow + (((0 * 2 + h) ^ l7) << 3);
    const int koff1 = krow + (((1 * 2 + h) ^ l7) << 3);
    const int koff2 = krow + (((2 * 2 + h) ^ l7) << 3);
    const int koff3 = krow + (((3 * 2 + h) ^ l7) << 3);
    const int vr0 = l31 * 64, vr1 = (l31 + 32) * 64;   // V rows d, d+32 (row&7 == l7)
    const int voff00 = vr0 + (((khalf * 4 + 0 * 2 + h) ^ l7) << 3);
    const int voff01 = vr0 + (((khalf * 4 + 1 * 2 + h) ^ l7) << 3);
    const int voff10 = vr1 + (((khalf * 4 + 0 * 2 + h) ^ l7) << 3);
    const int voff11 = vr1 + (((khalf * 4 + 1 * 2 + h) ^ l7) << 3);

    auto COMPUTE = [&](const bf16_t* ks, const bf16_t* vs) {
        // S^T = K * Q^T : D[key=(reg&3)+8*(reg>>2)+4h][q=l31]
        floatx16 S = (floatx16)0.0f;
        __builtin_amdgcn_s_setprio(1);
        bf16x8 kf0 = *(const bf16x8*)(ks + koff0);
        S = __builtin_amdgcn_mfma_f32_32x32x16_bf16(kf0, qf0, S, 0, 0, 0);
        bf16x8 kf1 = *(const bf16x8*)(ks + koff1);
        S = __builtin_amdgcn_mfma_f32_32x32x16_bf16(kf1, qf1, S, 0, 0, 0);
        bf16x8 kf2 = *(const bf16x8*)(ks + koff2);
        S = __builtin_amdgcn_mfma_f32_32x32x16_bf16(kf2, qf2, S, 0, 0, 0);
        bf16x8 kf3 = *(const bf16x8*)(ks + koff3);
        S = __builtin_amdgcn_mfma_f32_32x32x16_bf16(kf3, qf3, S, 0, 0, 0);
        __builtin_amdgcn_s_setprio(0);

        // P = exp2(S); lane owns P[16 keys][q=l31]; partial row sum
        float pe[16];
#pragma unroll
        for (int r = 0; r < 16; ++r) {
            float p = __builtin_amdgcn_exp2f(S[r]);
            lacc += p;
            pe[r] = p;
        }
        // regs 0-3: keys 4h+0..3 | 4-7: 8+4h+.. | 8-11: 16+4h+.. | 12-15: 24+4h+..
        unsigned PA0 = pk2(pe[0],  pe[1]),  PA1 = pk2(pe[2],  pe[3]);
        unsigned PB0 = pk2(pe[4],  pe[5]),  PB1 = pk2(pe[6],  pe[7]);
        unsigned PC0 = pk2(pe[8],  pe[9]),  PC1 = pk2(pe[10], pe[11]);
        unsigned PD0 = pk2(pe[12], pe[13]), PD1 = pk2(pe[14], pe[15]);
        auto s0 = __builtin_amdgcn_permlane32_swap((int)PA0, (int)PB0, false, false);
        auto s1 = __builtin_amdgcn_permlane32_swap((int)PA1, (int)PB1, false, false);
        auto s2 = __builtin_amdgcn_permlane32_swap((int)PC0, (int)PD0, false, false);
        auto s3 = __builtin_amdgcn_permlane32_swap((int)PC1, (int)PD1, false, false);
        uintx4 f0, f1;
        f0.x = (unsigned)s0[0]; f0.y = (unsigned)s1[0]; f0.z = (unsigned)s0[1]; f0.w = (unsigned)s1[1];
        f1.x = (unsigned)s2[0]; f1.y = (unsigned)s3[0]; f1.z = (unsigned)s2[1]; f1.w = (unsigned)s3[1];
        bf16x8 frag0 = __builtin_bit_cast(bf16x8, f0);   // keys h*8+0..7   (slice 0)
        bf16x8 frag1 = __builtin_bit_cast(bf16x8, f1);   // keys 16+h*8+0..7 (slice 1)

        // O += P * V : A[q][key]=frag, B[key][d]=Vs[d][key] reads
        __builtin_amdgcn_s_setprio(1);
        bf16x8 vf00 = *(const bf16x8*)(vs + voff00);
        O0 = __builtin_amdgcn_mfma_f32_32x32x16_bf16(frag0, vf00, O0, 0, 0, 0);
        bf16x8 vf01 = *(const bf16x8*)(vs + voff01);
        O0 = __builtin_amdgcn_mfma_f32_32x32x16_bf16(frag1, vf01, O0, 0, 0, 0);
        bf16x8 vf10 = *(const bf16x8*)(vs + voff10);
        O1 = __builtin_amdgcn_mfma_f32_32x32x16_bf16(frag0, vf10, O1, 0, 0, 0);
        bf16x8 vf11 = *(const bf16x8*)(vs + voff11);
        O1 = __builtin_amdgcn_mfma_f32_32x32x16_bf16(frag1, vf11, O1, 0, 0, 0);
        __builtin_amdgcn_s_setprio(0);
    };

    STAGE(0, 0);

#pragma unroll 1
    for (int j = 0; j < 16; ++j) {
        // ---- tile kt = 2j (buf 0) ----
        __syncthreads();               // drains vmcnt: tile 2j ready; buf1 free
        STAGE(1, 2 * j + 1);
        COMPUTE(Ks[0], Vs[0]);
        // ---- tile kt = 2j+1 (buf 1) ----
        __syncthreads();
        if (j < 15) STAGE(0, 2 * j + 2);
        COMPUTE(Ks[1], Vs[1]);
    }

    // in-wave: merge the two lane-halves (each summed 16 of this khalf's 32 keys)
    lacc += __shfl_xor(lacc, 32, 64);   // lanes l, l+32 now both hold l(q=l31)

    // cross-khalf reduction of partial O and l via LDS (once)
    __syncthreads();                 // all tile reads done; Ks/Vs reusable
    float* obuf = (float*)Ks;        // 2 qhalf x 64 lanes x 32 f = 16 KB
    float* lbuf = (float*)Vs;        // 2 qhalf x 32 f
    const int obase = qhalf * 2048 + lane * 32;
    if (khalf == 1) {
#pragma unroll
        for (int g = 0; g < 4; ++g) {
            floatx4 v4;
#pragma unroll
            for (int e = 0; e < 4; ++e) v4[e] = O0[g * 4 + e];
            *(floatx4*)(obuf + obase + (((0 * 4 + g) ^ l7) << 2)) = v4;
        }
#pragma unroll
        for (int g = 0; g < 4; ++g) {
            floatx4 v4;
#pragma unroll
            for (int e = 0; e < 4; ++e) v4[e] = O1[g * 4 + e];
            *(floatx4*)(obuf + obase + (((1 * 4 + g) ^ l7) << 2)) = v4;
        }
        if (lane < 32) lbuf[qhalf * 32 + l31] = lacc;
    }
    __syncthreads();
    if (khalf == 0) {
#pragma unroll
        for (int g = 0; g < 4; ++g) {
            floatx4 v4 = *(const floatx4*)(obuf + obase + (((0 * 4 + g) ^ l7) << 2));
#pragma unroll
            for (int e = 0; e < 4; ++e) O0[g * 4 + e] += v4[e];
        }
#pragma unroll
        for (int g = 0; g < 4; ++g) {
            floatx4 v4 = *(const floatx4*)(obuf + obase + (((1 * 4 + g) ^ l7) << 2));
#pragma unroll
            for (int e = 0; e < 4; ++e) O1[g * 4 + e] += v4[e];
        }
        lacc += lbuf[qhalf * 32 + l31];

        // epilogue: out[b][n][hd*64 + d] = o / l
        float* ob = Out + (size_t)b * 2048 * 512 + (size_t)hd * 64;
#pragma unroll
        for (int r = 0; r < 16; ++r) {
            int qr = (r & 3) + 8 * (r >> 2) + 4 * h;       // q row of reg r
            float lr = __shfl(lacc, qr, 64);
            float inv = 1.0f / lr;
            float* orow = ob + (size_t)(qt * 64 + qhalf * 32 + qr) * 512;
            orow[l31]      = O0[r] * inv;
            orow[32 + l31] = O1[r] * inv;
        }
    }
}

// -------------------- launch --------------------
extern "C" void kernel_launch(void* const* d_in, const int* in_sizes, int n_in,
                              void* d_out, int out_size, void* d_ws, size_t ws_size,
                              hipStream_t stream) {
    const float* x = (const float*)d_in[0];   // [4,2048,512]
    const float* w = (const float*)d_in[1];   // [1536,512]
    float* out = (float*)d_out;               // [4,2048,512]

    char* ws = (char*)d_ws;
    bf16_t* xb = (bf16_t*)(ws);                       //  8 MB
    bf16_t* wb = (bf16_t*)(ws + 8388608);             //  1.5 MB
    bf16_t* q  = (bf16_t*)(ws + 9961472);             //  8 MB
    bf16_t* k  = (bf16_t*)(ws + 18350080);            //  8 MB
    bf16_t* vt = (bf16_t*)(ws + 26738688);            //  8 MB (end 33.5 MB)

    convert_kernel<<<4864, 256, 0, stream>>>(x, xb, w, wb, 1048576);
    qkv_gemm<<<dim3(64, 12), 256, 0, stream>>>(xb, wb, q, k, vt);
    flash_attn<<<dim3(32, 32), 256, 0, stream>>>(q, k, vt, out);
}

// Round 5
// 140.864 us; speedup vs baseline: 1.0451x; 1.0451x over previous
//
#include <hip/hip_runtime.h>
#include <hip/hip_bf16.h>
#include <stdint.h>

typedef __bf16 bf16_t;
typedef float floatx4 __attribute__((ext_vector_type(4)));
typedef __bf16 bf16x8 __attribute__((ext_vector_type(8)));
typedef __bf16 bf16x4 __attribute__((ext_vector_type(4)));
typedef unsigned int uintx4 __attribute__((ext_vector_type(4)));

// scale = DH^-0.5 * log2(e), folded into Q at GEMM epilogue so softmax uses raw exp2
#define QSCALE 0.1803368801111204f

// -------------------- async global->LDS (16B) --------------------
__device__ __forceinline__ void gl2lds16(const bf16_t* g, bf16_t* l) {
    __builtin_amdgcn_global_load_lds(
        (const __attribute__((address_space(1))) unsigned int*)g,
        (__attribute__((address_space(3))) unsigned int*)l,
        16, 0, 0);
}

// pack two f32 -> one dword of 2 bf16 (scalar casts; compiler fuses well, m240)
__device__ __forceinline__ unsigned pk2(float lo, float hi) {
    unsigned short a = __builtin_bit_cast(unsigned short, (bf16_t)lo);
    unsigned short b = __builtin_bit_cast(unsigned short, (bf16_t)hi);
    return (unsigned)a | ((unsigned)b << 16);
}

// -------------------- fp32 -> bf16 convert (x and W fused) --------------------
__global__ __launch_bounds__(256) void convert_kernel(const float* __restrict__ x,
                                                      bf16_t* __restrict__ xb,
                                                      const float* __restrict__ w,
                                                      bf16_t* __restrict__ wb,
                                                      int nx4) {   // x chunks; W chunks follow
    int i = blockIdx.x * 256 + threadIdx.x;
    const float* in; bf16_t* out; int j;
    if (i < nx4) { in = x; out = xb; j = i; }
    else         { in = w; out = wb; j = i - nx4; }
    float4 v = ((const float4*)in)[j];
    bf16x4 o;
    o.x = (bf16_t)v.x; o.y = (bf16_t)v.y; o.z = (bf16_t)v.z; o.w = (bf16_t)v.w;
    ((bf16x4*)out)[j] = o;
}

// -------------------- QKV projection GEMM (gemm_bt) --------------------
// R10: the non-flash segment has been ~90us for 5 rounds (ideal ~20-25us) ->
// qkv_gemm is the hidden cost. Old loop: sync; stage; sync; compute -- the 2nd
// barrier's vmcnt(0) drain sits right after the global_load_lds issues: full
// L2/HBM latency exposed 8x per block.
// Fix: 128x64 tile, grid 1536 (= exactly 2 balanced rounds at 3 blocks/CU),
// double-buffered LDS (48KB -> 3 blocks/CU), ONE barrier per K-step with
// next-tile staging issued before compute (flash_attn/T3 pattern).
// XCD swizzle: XCD x owns bx in [8x,8x+8) x all 24 by -> X panel 1MB + W 1.5MB
// resident in local L2.
__global__ __launch_bounds__(256, 3) void qkv_gemm(const bf16_t* __restrict__ X,   // [8192][512]
                                                   const bf16_t* __restrict__ W,   // [1536][512]
                                                   bf16_t* __restrict__ Q,         // [32][2048][64] (pre-scaled)
                                                   bf16_t* __restrict__ K,         // [32][2048][64]
                                                   bf16_t* __restrict__ Vt)        // [32][64][2048]
{
    __shared__ bf16_t As[2][128 * 64];   // 2 x 16 KB
    __shared__ bf16_t Bs[2][64 * 64];    // 2 x  8 KB   (total 48 KB -> 3 blocks/CU)

    const int tid  = threadIdx.x;
    const int wave = tid >> 6;
    const int lane = tid & 63;
    const int quad = lane >> 4;
    const int lrow = lane & 15;
    const int t7g  = lrow & 7;      // = row&7 of every fragment row this lane touches
    const int wbase = tid & 192;    // wave*64, wave-uniform

    // XCD swizzle over 1536 blocks: consecutive raw round-robin XCDs, so
    // XCD (raw&7) gets id = raw>>3 in 0..191 -> bx = xcd*8 + id/24, by = id%24.
    int raw = blockIdx.x;
    int xcd = raw & 7;
    int idx = raw >> 3;
    int bx  = xcd * 8 + idx / 24;
    int by  = idx - (idx / 24) * 24;
    const int bm0 = bx * 128;
    const int bn0 = by * 64;
    const int mw = (wave >> 1) * 64;
    const int nw = (wave & 1) * 32;

    floatx4 acc[4][2];
#pragma unroll
    for (int i = 0; i < 4; i++)
#pragma unroll
        for (int j = 0; j < 2; j++) acc[i][j] = (floatx4)0.0f;

    // hoisted staging geometry: A = 1024 chunks (128r x 8kc), B = 512 chunks
    const bf16_t* xb  = X + (size_t)bm0 * 512;
    const bf16_t* wbp = W + (size_t)bn0 * 512;
    const bf16_t* srcA[4];
    const bf16_t* srcB[2];
#pragma unroll
    for (int r = 0; r < 4; ++r) {
        int c = r * 256 + tid;
        int row = c >> 3, kc = c & 7;
        int skc = kc ^ (row & 7);              // swizzled source chunk
        srcA[r] = xb + (size_t)row * 512 + skc * 8;
    }
#pragma unroll
    for (int r = 0; r < 2; ++r) {
        int c = r * 256 + tid;
        int row = c >> 3, kc = c & 7;
        int skc = kc ^ (row & 7);
        srcB[r] = wbp + (size_t)row * 512 + skc * 8;
    }

    auto STAGE = [&](int bufI, int k0) {
#pragma unroll
        for (int r = 0; r < 4; ++r)
            gl2lds16(srcA[r] + k0, As[bufI] + (size_t)(r * 256 + wbase) * 8);
#pragma unroll
        for (int r = 0; r < 2; ++r)
            gl2lds16(srcB[r] + k0, Bs[bufI] + (size_t)(r * 256 + wbase) * 8);
    };

    STAGE(0, 0);

#pragma unroll 1
    for (int kb = 0; kb < 8; ++kb) {
        const int buf = kb & 1;
        __syncthreads();                 // drains vmcnt: tile kb staged; prev compute done
        if (kb < 7) STAGE(buf ^ 1, (kb + 1) * 64);

        const bf16_t* as = As[buf];
        const bf16_t* bs = Bs[buf];
#pragma unroll
        for (int ks = 0; ks < 2; ++ks) {
            bf16x8 af[4], bfr[2];
#pragma unroll
            for (int mi = 0; mi < 4; mi++)
                af[mi] = *(const bf16x8*)(as + (mw + mi * 16 + lrow) * 64 + (((ks * 4 + quad) ^ t7g) << 3));
#pragma unroll
            for (int ni = 0; ni < 2; ni++)
                bfr[ni] = *(const bf16x8*)(bs + (nw + ni * 16 + lrow) * 64 + (((ks * 4 + quad) ^ t7g) << 3));
            __builtin_amdgcn_s_setprio(1);
#pragma unroll
            for (int mi = 0; mi < 4; mi++)
#pragma unroll
                for (int ni = 0; ni < 2; ni++)
                    acc[mi][ni] = __builtin_amdgcn_mfma_f32_16x16x32_bf16(af[mi], bfr[ni], acc[mi][ni], 0, 0, 0);
            __builtin_amdgcn_s_setprio(0);
        }
    }

    // epilogue: C/D layout col=lane&15, row=quad*4+reg  [verified m89]
#pragma unroll
    for (int mi = 0; mi < 4; mi++) {
        int mbase = bm0 + mw + mi * 16 + quad * 4;
        int b = mbase >> 11, n = mbase & 2047;   // r never crosses batch boundary (mbase%4==0)
#pragma unroll
        for (int ni = 0; ni < 2; ni++) {
            int o = bn0 + nw + ni * 16 + lrow;
            int s  = o >> 9;
            int h  = (o >> 6) & 7;
            int dh = o & 63;
            int bh = b * 8 + h;
            if (s == 2) {
                bf16x4 pv;
#pragma unroll
                for (int r = 0; r < 4; r++) pv[r] = (bf16_t)acc[mi][ni][r];
                *(bf16x4*)(Vt + ((size_t)bh * 64 + dh) * 2048 + n) = pv;   // 8B packed
            } else if (s == 0) {
#pragma unroll
                for (int r = 0; r < 4; r++)
                    Q[((size_t)bh * 2048 + n + r) * 64 + dh] = (bf16_t)(acc[mi][ni][r] * QSCALE);
            } else {
#pragma unroll
                for (int r = 0; r < 4; r++)
                    K[((size_t)bh * 2048 + n + r) * 64 + dh] = (bf16_t)acc[mi][ni][r];
            }
        }
    }
}

// -------------------- flash attention --------------------
// R10: revert to R8 structure (16x16 MFMA, proven 0 bank conflicts, 55.6us)
// + keep R9's XCD swizzle only (proven: FETCH 69.7 -> 12.3 MB).
// R8 mechanism: swapped QK^T (mfma(K,Q)) + quad-bit-swap K row map + two
// permlane32_swap assemble the PV A-frag in registers; P never touches LDS.
__device__ __forceinline__ void stage_tile(const bf16_t* __restrict__ kb,
                                           const bf16_t* __restrict__ vb,
                                           int kt, bf16_t* ksbuf, bf16_t* vsbuf,
                                           int wave, int lane) {
#pragma unroll
    for (int part = 0; part < 2; ++part) {
        int ch  = part * 256 + wave * 64 + lane;   // chunk id 0..511
        int row = ch >> 3, cc = ch & 7;
        int scc = cc ^ (row & 7);                  // swizzled source chunk
        bf16_t* ldst = ksbuf + (size_t)(part * 256 + wave * 64) * 8;  // wave-uniform
        gl2lds16(kb + ((size_t)(kt * 64 + row)) * 64 + scc * 8, ldst);
        bf16_t* ldst2 = vsbuf + (size_t)(part * 256 + wave * 64) * 8;
        gl2lds16(vb + (size_t)row * 2048 + kt * 64 + scc * 8, ldst2);
    }
}

__global__ __launch_bounds__(256, 5) void flash_attn(const bf16_t* __restrict__ Q,   // [32][2048][64], pre-scaled
                                                     const bf16_t* __restrict__ K,   // [32][2048][64]
                                                     const bf16_t* __restrict__ Vt,  // [32][64][2048]
                                                     float* __restrict__ Out)        // [4][2048][512]
{
    __shared__ bf16_t Ks[2][64 * 64];   // 16 KB
    __shared__ bf16_t Vs[2][64 * 64];   // 16 KB
    // total 32768 B -> 5 blocks/CU

    const int tid  = threadIdx.x;
    const int wave = tid >> 6;
    const int lane = tid & 63;
    const int quad = lane >> 4;
    const int c    = lane & 15;
    const int t7   = c & 7;
    const int qhalf = wave >> 1;   // which 32 q-rows
    const int khalf = wave & 1;    // which 32 keys of each 64-key tile

    // XCD swizzle (R9-proven): XCD (raw&7) owns bh group of 4
    int raw = blockIdx.x + (blockIdx.y << 5);
    int swz = (raw & 7) * 128 + (raw >> 3);
    const int qt = swz & 31;
    const int bh = swz >> 5;
    const int b = bh >> 3, h = bh & 7;

    // K A-operand row map: m=c -> key row bw = quad-bit-swapped c (bijective 0..15)
    const int bw    = ((c & 4) << 1) | ((c & 8) >> 1) | (c & 3);
    const int brow7 = bw & 7;

    // Q fragments (B-operand: n=lane&15=q-col, k=quad*8+j), shifted-query source row.
    bf16x8 qf[2][2];
#pragma unroll
    for (int mt = 0; mt < 2; ++mt) {
        int qg  = qt * 64 + qhalf * 32 + mt * 16 + c;
        int src = (qg == 0) ? 0 : qg - 1;
        const bf16_t* qbase = Q + ((size_t)bh * 2048 + src) * 64;
        qf[mt][0] = *(const bf16x8*)(qbase + quad * 8);
        qf[mt][1] = *(const bf16x8*)(qbase + 32 + quad * 8);
    }

    floatx4 o[2][4];
#pragma unroll
    for (int mt = 0; mt < 2; ++mt)
#pragma unroll
        for (int i = 0; i < 4; i++) o[mt][i] = (floatx4)0.0f;
    float lacc[2] = {0.f, 0.f};

    const bf16_t* kb = K + ((size_t)bh * 2048) * 64;
    const bf16_t* vb = Vt + ((size_t)bh * 64) * 2048;

    stage_tile(kb, vb, 0, Ks[0], Vs[0], wave, lane);

#pragma unroll 1
    for (int kt = 0; kt < 32; ++kt) {
        const int buf = kt & 1;
        __syncthreads();   // drains vmcnt: tile kt ready; all waves done reading buf^1
        if (kt < 31)
            stage_tile(kb, vb, kt + 1, Ks[buf ^ 1], Vs[buf ^ 1], wave, lane);

        const bf16_t* ks = Ks[buf];
        const bf16_t* vs = Vs[buf];

        // S^T = K * Q^T : D[key=quad*4+r][q=c]; K rows via bw map.
        floatx4 s[2][2];
        __builtin_amdgcn_s_setprio(1);
#pragma unroll
        for (int nt = 0; nt < 2; ++nt) {
            const bf16_t* krow = ks + (khalf * 32 + nt * 16 + bw) * 64;
            bf16x8 kf0 = *(const bf16x8*)(krow + ((quad ^ brow7) << 3));
            bf16x8 kf1 = *(const bf16x8*)(krow + (((4 + quad) ^ brow7) << 3));
#pragma unroll
            for (int mt = 0; mt < 2; ++mt) {
                floatx4 t = (floatx4)0.0f;
                t = __builtin_amdgcn_mfma_f32_16x16x32_bf16(kf0, qf[mt][0], t, 0, 0, 0);
                t = __builtin_amdgcn_mfma_f32_16x16x32_bf16(kf1, qf[mt][1], t, 0, 0, 0);
                s[mt][nt] = t;
            }
        }
        __builtin_amdgcn_s_setprio(0);

        // P = exp2(S); per-lane partial row sum (q=c); in-register PV A-frags
        bf16x8 pfrag[2];
#pragma unroll
        for (int mt = 0; mt < 2; ++mt) {
            float pe[2][4];
#pragma unroll
            for (int nt = 0; nt < 2; ++nt)
#pragma unroll
                for (int r = 0; r < 4; ++r) {
                    float p = __builtin_amdgcn_exp2f(s[mt][nt][r]);
                    lacc[mt] += p;
                    pe[nt][r] = p;
                }
            unsigned A0 = pk2(pe[0][0], pe[0][1]);
            unsigned A1 = pk2(pe[0][2], pe[0][3]);
            unsigned B0 = pk2(pe[1][0], pe[1][1]);
            unsigned B1 = pk2(pe[1][2], pe[1][3]);
            auto r0 = __builtin_amdgcn_permlane32_swap((int)A0, (int)B0, false, false);
            auto r1 = __builtin_amdgcn_permlane32_swap((int)A1, (int)B1, false, false);
            uintx4 fd;
            fd.x = (unsigned)r0[0];
            fd.y = (unsigned)r1[0];
            fd.z = (unsigned)r0[1];
            fd.w = (unsigned)r1[1];
            pfrag[mt] = __builtin_bit_cast(bf16x8, fd);
        }

        // O += P * V (contraction over this wave's 32 keys, A-frag in registers)
        __builtin_amdgcn_s_setprio(1);
#pragma unroll
        for (int sub = 0; sub < 4; ++sub) {
            const bf16_t* vrow = vs + (sub * 16 + c) * 64;      // row&7 == t7
            bf16x8 vf = *(const bf16x8*)(vrow + (((khalf * 4 + quad) ^ t7) << 3));
            o[0][sub] = __builtin_amdgcn_mfma_f32_16x16x32_bf16(pfrag[0], vf, o[0][sub], 0, 0, 0);
            o[1][sub] = __builtin_amdgcn_mfma_f32_16x16x32_bf16(pfrag[1], vf, o[1][sub], 0, 0, 0);
        }
        __builtin_amdgcn_s_setprio(0);
    }

    // in-wave reduction over the 4 key-quads: butterfly xor16 + xor32
#pragma unroll
    for (int mt = 0; mt < 2; ++mt) {
        lacc[mt] += __shfl_xor(lacc[mt], 16, 64);
        lacc[mt] += __shfl_xor(lacc[mt], 32, 64);
    }

    // cross-khalf reduction of partial O and l via LDS (once)
    __syncthreads();                 // all tile reads done; Ks/Vs reusable
    float* obuf = (float*)Ks;        // 2 qhalf x 2048 f32 = 16 KB
    float* lbuf = (float*)Vs;        // 2 qhalf x 32 f32
    if (khalf == 1) {
#pragma unroll
        for (int mt = 0; mt < 2; ++mt)
#pragma unroll
            for (int sub = 0; sub < 4; ++sub)
                *(floatx4*)(obuf + qhalf * 2048 + (mt * 4 + sub) * 256 + lane * 4) = o[mt][sub];
        if (lane < 16) {             // quad0 lanes: lacc holds l(q = mt*16+c)
#pragma unroll
            for (int mt = 0; mt < 2; ++mt)
                lbuf[qhalf * 32 + mt * 16 + c] = lacc[mt];
        }
    }
    __syncthreads();
    if (khalf == 0) {
#pragma unroll
        for (int mt = 0; mt < 2; ++mt)
#pragma unroll
            for (int sub = 0; sub < 4; ++sub)
                o[mt][sub] += *(const floatx4*)(obuf + qhalf * 2048 + (mt * 4 + sub) * 256 + lane * 4);
#pragma unroll
        for (int mt = 0; mt < 2; ++mt)
            lacc[mt] += lbuf[qhalf * 32 + mt * 16 + c];

        // epilogue: out[b][n][h*64 + d] = o / l ; l for row q=quad*4+r via shfl
        float* ob = Out + (size_t)b * 2048 * 512 + (size_t)h * 64;
#pragma unroll
        for (int mt = 0; mt < 2; ++mt) {
            int n0 = qt * 64 + qhalf * 32 + mt * 16 + quad * 4;
#pragma unroll
            for (int r = 0; r < 4; r++) {
                float lr = __shfl(lacc[mt], quad * 4 + r, 64);
                float inv = 1.0f / lr;
                float* orow = ob + (size_t)(n0 + r) * 512;
#pragma unroll
                for (int sub = 0; sub < 4; ++sub)
                    orow[sub * 16 + c] = o[mt][sub][r] * inv;
            }
        }
    }
}

// -------------------- launch --------------------
extern "C" void kernel_launch(void* const* d_in, const int* in_sizes, int n_in,
                              void* d_out, int out_size, void* d_ws, size_t ws_size,
                              hipStream_t stream) {
    const float* x = (const float*)d_in[0];   // [4,2048,512]
    const float* w = (const float*)d_in[1];   // [1536,512]
    float* out = (float*)d_out;               // [4,2048,512]

    char* ws = (char*)d_ws;
    bf16_t* xb = (bf16_t*)(ws);                       //  8 MB
    bf16_t* wb = (bf16_t*)(ws + 8388608);             //  1.5 MB
    bf16_t* q  = (bf16_t*)(ws + 9961472);             //  8 MB
    bf16_t* k  = (bf16_t*)(ws + 18350080);            //  8 MB
    bf16_t* vt = (bf16_t*)(ws + 26738688);            //  8 MB (end 33.5 MB)

    convert_kernel<<<4864, 256, 0, stream>>>(x, xb, w, wb, 1048576);
    qkv_gemm<<<1536, 256, 0, stream>>>(xb, wb, q, k, vt);
    flash_attn<<<dim3(32, 32), 256, 0, stream>>>(q, k, vt, out);
}